// Round 6
// baseline (435.044 us; speedup 1.0000x reference)
//
#include <hip/hip_runtime.h>
#include <hip/hip_bf16.h>

#define DIM 128
#define KCODES 1024
#define BROWS 128        // rows per block (4 waves x 32 rows)
#define TAU 2e-3f

typedef __attribute__((ext_vector_type(8))) short bf16x8;
typedef __attribute__((ext_vector_type(4))) float f32x4;

__device__ __forceinline__ unsigned short f2bf(float x, float* back) {
    __hip_bfloat16 h = __float2bfloat16(x);   // RNE
    *back = __bfloat162float(h);
    union { __hip_bfloat16 hh; unsigned short u; } cv; cv.hh = h;
    return cv.u;
}

// ---------- prep: E -> bf16 hi/lo (linear layout) + ||e||^2, fused ----------
__global__ void pack_kernel(const float* __restrict__ embed, unsigned short* __restrict__ Ehi,
                            unsigned short* __restrict__ Elo, float* __restrict__ enorm) {
    int t = blockIdx.x * blockDim.x + threadIdx.x;   // 0 .. KCODES*16-1
    int k = t >> 4;
    int s = t & 15;
    const float* src = embed + (size_t)k * DIM + s * 8;
    float4 a0 = *(const float4*)src;
    float4 a1 = *(const float4*)(src + 4);
    float f[8] = {a0.x, a0.y, a0.z, a0.w, a1.x, a1.y, a1.z, a1.w};
    bf16x8 h8, l8;
    float ps = 0.f;
#pragma unroll
    for (int j = 0; j < 8; ++j) {
        float bk, dd;
        h8[j] = (short)f2bf(f[j], &bk);
        l8[j] = (short)f2bf(f[j] - bk, &dd);
        ps = fmaf(f[j], f[j], ps);
    }
    *(bf16x8*)&Ehi[(size_t)k * DIM + s * 8] = h8;
    *(bf16x8*)&Elo[(size_t)k * DIM + s * 8] = l8;
#pragma unroll
    for (int mask = 1; mask < 16; mask <<= 1) ps += __shfl_xor(ps, mask);
    if (s == 0) enorm[k] = ps;
}

#define MF(A, B, C) C = __builtin_amdgcn_mfma_f32_16x16x32_bf16(A, B, C, 0, 0, 0)

// load A fragment (one s,ks cell) into named scalars H,L
#define LOADA(H, L, S, KS) { \
    const float* xp_ = x + (row0 + w * 32 + (S) * 16 + n) * DIM + (KS) * 32 + q * 8; \
    float4 a0_ = *(const float4*)xp_; \
    float4 a1_ = *(const float4*)(xp_ + 4); \
    float bk_, dd_; bf16x8 h8_, l8_; \
    h8_[0] = (short)f2bf(a0_.x, &bk_); l8_[0] = (short)f2bf(a0_.x - bk_, &dd_); \
    h8_[1] = (short)f2bf(a0_.y, &bk_); l8_[1] = (short)f2bf(a0_.y - bk_, &dd_); \
    h8_[2] = (short)f2bf(a0_.z, &bk_); l8_[2] = (short)f2bf(a0_.z - bk_, &dd_); \
    h8_[3] = (short)f2bf(a0_.w, &bk_); l8_[3] = (short)f2bf(a0_.w - bk_, &dd_); \
    h8_[4] = (short)f2bf(a1_.x, &bk_); l8_[4] = (short)f2bf(a1_.x - bk_, &dd_); \
    h8_[5] = (short)f2bf(a1_.y, &bk_); l8_[5] = (short)f2bf(a1_.y - bk_, &dd_); \
    h8_[6] = (short)f2bf(a1_.z, &bk_); l8_[6] = (short)f2bf(a1_.z - bk_, &dd_); \
    h8_[7] = (short)f2bf(a1_.w, &bk_); l8_[7] = (short)f2bf(a1_.w - bk_, &dd_); \
    H = h8_; L = l8_; }

// prefetch one 16-code tile's B fragments (hi+lo) into 8 named scalars
#define LOADB(BH0, BH1, BH2, BH3, BL0, BL1, BL2, BL3, T) { \
    const unsigned short* ph_ = bh_base + (size_t)(T) * 2048; \
    const unsigned short* pl_ = bl_base + (size_t)(T) * 2048; \
    BH0 = *(const bf16x8*)(ph_);      BH1 = *(const bf16x8*)(ph_ + 32); \
    BH2 = *(const bf16x8*)(ph_ + 64); BH3 = *(const bf16x8*)(ph_ + 96); \
    BL0 = *(const bf16x8*)(pl_);      BL1 = *(const bf16x8*)(pl_ + 32); \
    BL2 = *(const bf16x8*)(pl_ + 64); BL3 = *(const bf16x8*)(pl_ + 96); }

#define UPD(BS, SE, BI, SC) { \
    if ((SC) > BS) { SE = BS; BS = (SC); BI = code_; } \
    else if ((SC) > SE) SE = (SC); }

// one 16-code tile: 24 MFMA + top-2 update, all operands named scalars
#define TILE_STEP(T, EN, BH0, BH1, BH2, BH3, BL0, BL1, BL2, BL3) { \
    f32x4 acc0_ = {0.f, 0.f, 0.f, 0.f}; \
    f32x4 acc1_ = {0.f, 0.f, 0.f, 0.f}; \
    MF(ah00, BH0, acc0_); MF(ah10, BH0, acc1_); \
    MF(al00, BH0, acc0_); MF(al10, BH0, acc1_); \
    MF(ah00, BL0, acc0_); MF(ah10, BL0, acc1_); \
    MF(ah01, BH1, acc0_); MF(ah11, BH1, acc1_); \
    MF(al01, BH1, acc0_); MF(al11, BH1, acc1_); \
    MF(ah01, BL1, acc0_); MF(ah11, BL1, acc1_); \
    MF(ah02, BH2, acc0_); MF(ah12, BH2, acc1_); \
    MF(al02, BH2, acc0_); MF(al12, BH2, acc1_); \
    MF(ah02, BL2, acc0_); MF(ah12, BL2, acc1_); \
    MF(ah03, BH3, acc0_); MF(ah13, BH3, acc1_); \
    MF(al03, BH3, acc0_); MF(al13, BH3, acc1_); \
    MF(ah03, BL3, acc0_); MF(ah13, BL3, acc1_); \
    int code_ = (T) * 16 + n; \
    float ne_ = -(EN); \
    float s0_, s1_; \
    s0_ = fmaf(2.f, acc0_[0], ne_); s1_ = fmaf(2.f, acc1_[0], ne_); \
    UPD(bs00, se00, bi00, s0_); UPD(bs10, se10, bi10, s1_); \
    s0_ = fmaf(2.f, acc0_[1], ne_); s1_ = fmaf(2.f, acc1_[1], ne_); \
    UPD(bs01, se01, bi01, s0_); UPD(bs11, se11, bi11, s1_); \
    s0_ = fmaf(2.f, acc0_[2], ne_); s1_ = fmaf(2.f, acc1_[2], ne_); \
    UPD(bs02, se02, bi02, s0_); UPD(bs12, se12, bi12, s1_); \
    s0_ = fmaf(2.f, acc0_[3], ne_); s1_ = fmaf(2.f, acc1_[3], ne_); \
    UPD(bs03, se03, bi03, s0_); UPD(bs13, se13, bi13, s1_); }

#define RED(BS, SE, BI) { \
    float ob_ = __shfl_xor(BS, mask); \
    float os_ = __shfl_xor(SE, mask); \
    int   oi_ = __shfl_xor(BI, mask); \
    if (ob_ > BS || (ob_ == BS && oi_ < BI)) { SE = fmaxf(BS, os_); BS = ob_; BI = oi_; } \
    else { SE = fmaxf(SE, ob_); } }

#define EMIT(BS, SE, BI, S, RG) { \
    int r_ = w * 32 + (S) * 16 + q * 4 + (RG); \
    idx_l[r_] = BI; \
    if (BS - SE < TAU) { int p_ = atomicAdd(&fcnt, 1); flist[p_] = r_; } }

// ---------- main: barrier-free B-streaming MFMA argmax, scratch-free codegen ----------
__global__ __launch_bounds__(256, 2)
void argmax_mfma_kernel(const float* __restrict__ x, const float* __restrict__ embed,
                        const unsigned short* __restrict__ Ehi, const unsigned short* __restrict__ Elo,
                        const float* __restrict__ enorm,
                        float* __restrict__ outq, float* __restrict__ outi) {
    __shared__ int idx_l[BROWS];
    __shared__ int flist[BROWS];
    __shared__ int fcnt;

    const int tid = threadIdx.x;
    const int w = tid >> 6;
    const int lane = tid & 63;
    const int n = lane & 15;         // code class / A-row class
    const int q = lane >> 4;         // k-segment (A/B) / row group (C)
    const size_t row0 = (size_t)blockIdx.x * BROWS;

    if (tid == 0) fcnt = 0;
    __syncthreads();

    // A fragments: named scalars -> guaranteed VGPR-resident
    bf16x8 ah00, ah01, ah02, ah03, ah10, ah11, ah12, ah13;
    bf16x8 al00, al01, al02, al03, al10, al11, al12, al13;
    LOADA(ah00, al00, 0, 0); LOADA(ah01, al01, 0, 1);
    LOADA(ah02, al02, 0, 2); LOADA(ah03, al03, 0, 3);
    LOADA(ah10, al10, 1, 0); LOADA(ah11, al11, 1, 1);
    LOADA(ah12, al12, 1, 2); LOADA(ah13, al13, 1, 3);

    // top-2 state: named scalars
    float bs00 = -3.4e38f, bs01 = -3.4e38f, bs02 = -3.4e38f, bs03 = -3.4e38f;
    float bs10 = -3.4e38f, bs11 = -3.4e38f, bs12 = -3.4e38f, bs13 = -3.4e38f;
    float se00 = -3.4e38f, se01 = -3.4e38f, se02 = -3.4e38f, se03 = -3.4e38f;
    float se10 = -3.4e38f, se11 = -3.4e38f, se12 = -3.4e38f, se13 = -3.4e38f;
    int bi00 = 0, bi01 = 0, bi02 = 0, bi03 = 0;
    int bi10 = 0, bi11 = 0, bi12 = 0, bi13 = 0;

    // B stream bases (shorts): B frag for (tile,ks) at tile*2048 + ks*32 (verified round 5)
    const unsigned short* bh_base = Ehi + n * DIM + q * 8;
    const unsigned short* bl_base = Elo + n * DIM + q * 8;

    bf16x8 p0h0, p0h1, p0h2, p0h3, p0l0, p0l1, p0l2, p0l3;
    bf16x8 p1h0, p1h1, p1h2, p1h3, p1l0, p1l1, p1l2, p1l3;

    float en0 = enorm[n], en1;
    LOADB(p0h0, p0h1, p0h2, p0h3, p0l0, p0l1, p0l2, p0l3, 0);

    for (int nt = 0; nt < KCODES / 16; nt += 2) {
        // prefetch tile nt+1 (+ its enorm) while computing tile nt — loads stay in flight
        en1 = enorm[(nt + 1) * 16 + n];
        LOADB(p1h0, p1h1, p1h2, p1h3, p1l0, p1l1, p1l2, p1l3, nt + 1);
        TILE_STEP(nt, en0, p0h0, p0h1, p0h2, p0h3, p0l0, p0l1, p0l2, p0l3);
        en0 = enorm[((nt + 2) & 63) * 16 + n];             // wrap: harmless re-read of tile 0
        LOADB(p0h0, p0h1, p0h2, p0h3, p0l0, p0l1, p0l2, p0l3, (nt + 2) & 63);
        TILE_STEP(nt + 1, en1, p1h0, p1h1, p1h2, p1h3, p1l0, p1l1, p1l2, p1l3);
    }

    // reduce top-2 across the 16 col-classes (lanes differing in bits 0..3)
#pragma unroll
    for (int mask = 1; mask < 16; mask <<= 1) {
        RED(bs00, se00, bi00); RED(bs01, se01, bi01);
        RED(bs02, se02, bi02); RED(bs03, se03, bi03);
        RED(bs10, se10, bi10); RED(bs11, se11, bi11);
        RED(bs12, se12, bi12); RED(bs13, se13, bi13);
    }
    if (n == 0) {
        EMIT(bs00, se00, bi00, 0, 0); EMIT(bs01, se01, bi01, 0, 1);
        EMIT(bs02, se02, bi02, 0, 2); EMIT(bs03, se03, bi03, 0, 3);
        EMIT(bs10, se10, bi10, 1, 0); EMIT(bs11, se11, bi11, 1, 1);
        EMIT(bs12, se12, bi12, 1, 2); EMIT(bs13, se13, bi13, 1, 3);
    }
    __syncthreads();

    // exact fp32 refine for near-tie rows (same arithmetic as the round-1 all-fp32 kernel)
    int nf = fcnt;
    for (int f = w; f < nf; f += 4) {
        int r = flist[f];
        const float4* xg4 = (const float4*)(x + (row0 + r) * DIM);
        float b = -3.4e38f; int bi = 0;
        for (int c = lane * 16; c < lane * 16 + 16; ++c) {
            const float4* eg4 = (const float4*)(embed + (size_t)c * DIM);
            float s = 0.f;
#pragma unroll 8
            for (int d = 0; d < DIM / 4; ++d) {
                float4 xv = xg4[d], ev = eg4[d];
                s = fmaf(xv.x, ev.x, s); s = fmaf(xv.y, ev.y, s);
                s = fmaf(xv.z, ev.z, s); s = fmaf(xv.w, ev.w, s);
            }
            float sc = fmaf(2.f, s, -enorm[c]);
            if (sc > b) { b = sc; bi = c; }
        }
#pragma unroll
        for (int mask = 1; mask < 64; mask <<= 1) {
            float ob = __shfl_xor(b, mask);
            int   oi = __shfl_xor(bi, mask);
            if (ob > b || (ob == b && oi < bi)) { b = ob; bi = oi; }
        }
        if (lane == 0) idx_l[r] = bi;
    }
    __syncthreads();

    // fused gather (embed is L2-resident) + float index write
    const float4* e4 = (const float4*)embed;
    float4* oq4 = (float4*)outq + row0 * (DIM / 4);
#pragma unroll
    for (int i = 0; i < 16; ++i) {
        int g = tid + i * 256;
        int r = g >> 5, d4 = g & 31;
        int id = idx_l[r];
        oq4[g] = e4[(size_t)id * (DIM / 4) + d4];
    }
    if (tid < BROWS) outi[row0 + tid] = (float)idx_l[tid];
}

extern "C" void kernel_launch(void* const* d_in, const int* in_sizes, int n_in,
                              void* d_out, int out_size, void* d_ws, size_t ws_size,
                              hipStream_t stream) {
    const float* x     = (const float*)d_in[0];
    const float* embed = (const float*)d_in[1];
    const int x_elems  = in_sizes[0];          // 12,288,000
    const int n_rows   = x_elems / DIM;        // 96,000

    float*          enorm = (float*)d_ws;                                   // 4 KB
    unsigned short* Ehi   = (unsigned short*)((char*)d_ws + 4096);          // 256 KB
    unsigned short* Elo   = Ehi + (size_t)KCODES * DIM;                     // 256 KB

    float* outq = (float*)d_out;
    float* outi = (float*)d_out + (size_t)x_elems;

    pack_kernel<<<KCODES * 16 / 256, 256, 0, stream>>>(embed, Ehi, Elo, enorm);
    argmax_mfma_kernel<<<n_rows / BROWS, 256, 0, stream>>>(x, embed, Ehi, Elo, enorm, outq, outi);
}